// Round 19
// baseline (1265.150 us; speedup 1.0000x reference)
//
#include <hip/hip_runtime.h>
#include <hip/hip_bf16.h>
#include <math.h>

#define B 32
#define S 512
#define W 8
#define CE 100       // CHAR_EMB
#define SE 100       // SUB_EMB
#define HD 200       // hidden per direction
#define G4 800       // 4*HD
#define IN2 200      // 2*CHAR_EMB
#define SUBV 100000
#define UNK 1
#define NL 4
#define SK (S - 2)   // 510
#define FEAT 500     // 2*HD + SE

typedef _Float16 h2_t __attribute__((ext_vector_type(2)));

__device__ __forceinline__ float fsig(float x) {
    return 1.f / (1.f + __expf(-x));
}
__device__ __forceinline__ float ftanh(float x) {
    float e = __expf(-2.f * fabsf(x));   // e in (0,1], overflow-safe
    float r = (1.f - e) / (1.f + e);
    return copysignf(r, x);
}

// 64-lane sum; result valid in lane 63. DPP adds run on the VALU pipe.
__device__ __forceinline__ float wave_sum64(float v) {
#if __has_builtin(__builtin_amdgcn_update_dpp)
#define DPPADD(C) { int x_ = __builtin_amdgcn_update_dpp(0, __float_as_int(v), C, 0xf, 0xf, true); \
                    v += __int_as_float(x_); }
    DPPADD(0x111)  // row_shr:1
    DPPADD(0x112)  // row_shr:2
    DPPADD(0x114)  // row_shr:4
    DPPADD(0x118)  // row_shr:8  -> lane15/31/47/63 hold row sums
    DPPADD(0x142)  // row_bcast15 -> lane31 = rows0+1, lane63 = rows2+3
    DPPADD(0x143)  // row_bcast31 -> lane63 = total
#undef DPPADD
    return v;
#else
    v += __shfl_xor(v, 1);  v += __shfl_xor(v, 2);  v += __shfl_xor(v, 4);
    v += __shfl_xor(v, 8);  v += __shfl_xor(v, 16); v += __shfl_xor(v, 32);
    return v;
#endif
}

__device__ __forceinline__ float dot4(float4 w, float4 h) {
    return fmaf(w.w, h.w, fmaf(w.z, h.z, fmaf(w.y, h.y, w.x * h.x)));
}

// packed-f16 2-way dot with f32 accumulate (v_dot2_f32_f16)
__device__ __forceinline__ float dot2f(unsigned a, unsigned b, float c) {
#if __has_builtin(__builtin_amdgcn_fdot2)
    return __builtin_amdgcn_fdot2(__builtin_bit_cast(h2_t, a),
                                  __builtin_bit_cast(h2_t, b), c, false);
#else
    h2_t x = __builtin_bit_cast(h2_t, a);
    h2_t y = __builtin_bit_cast(h2_t, b);
    return c + (float)x[0] * (float)y[0] + (float)x[1] * (float)y[1];
#endif
}

// ------- K0: transpose + pack f16: Wih[800][200] -> WTh[100][800] u32 ----
__global__ void transpose_pack_k(const float* __restrict__ in, unsigned* __restrict__ out) {
    int o = blockIdx.x * 256 + threadIdx.x;   // 80000 elements
    if (o >= 100 * G4) return;
    int k2 = o / G4, g = o % G4;
    h2_t v;
    v[0] = (_Float16)in[g * 200 + 2 * k2];
    v[1] = (_Float16)in[g * 200 + 2 * k2 + 1];
    out[o] = __builtin_bit_cast(unsigned, v);
}

// ---------------- K2: fused embed + xg via v_dot2_f32_f16 ----------------
__global__ void xg_k(const int* __restrict__ chars, const int* __restrict__ bichars,
                     const float* __restrict__ cw, const float* __restrict__ bw,
                     const unsigned* __restrict__ WTh_f, const float* __restrict__ bf,
                     const unsigned* __restrict__ WTh_b, const float* __restrict__ bb,
                     float* __restrict__ xgf, float* __restrict__ xgb) {
    const int dir = blockIdx.y;
    const unsigned* WT = dir ? WTh_b : WTh_f;
    const float* bias  = dir ? bb : bf;
    float* out         = dir ? xgb : xgf;
    int r0 = blockIdx.x * 16;
    __shared__ unsigned xs2[16][100];
    for (int i = threadIdx.x; i < 16 * 100; i += 256) {
        int r = i / 100, c2 = i % 100;
        int row = r0 + r;                         // flat token index b*S+s
        float a, b;
        if (c2 < 50) {
            const float* p = cw + (size_t)chars[row] * CE + 2 * c2;
            a = p[0]; b = p[1];
        } else {
            const float* p = bw + (size_t)bichars[row] * CE + 2 * (c2 - 50);
            a = p[0]; b = p[1];
        }
        h2_t v; v[0] = (_Float16)a; v[1] = (_Float16)b;
        xs2[r][c2] = __builtin_bit_cast(unsigned, v);
    }
    __syncthreads();
    float acc[4][16];
    for (int q = 0; q < 4; q++)
        for (int r = 0; r < 16; r++) acc[q][r] = 0.f;
    int tid = threadIdx.x;
    for (int k2 = 0; k2 < 100; k2++) {
        const unsigned* wrow = WT + (size_t)k2 * G4;
        unsigned w0 = wrow[tid];
        unsigned w1 = wrow[tid + 256];
        unsigned w2 = wrow[tid + 512];
        unsigned w3 = (tid < 32) ? wrow[tid + 768] : 0u;
        for (int r = 0; r < 16; r++) {
            unsigned xv = xs2[r][k2];
            acc[0][r] = dot2f(w0, xv, acc[0][r]);
            acc[1][r] = dot2f(w1, xv, acc[1][r]);
            acc[2][r] = dot2f(w2, xv, acc[2][r]);
            acc[3][r] = dot2f(w3, xv, acc[3][r]);
        }
    }
    for (int q = 0; q < 4; q++) {
        int g = tid + q * 256;
        if (g < G4) {
            float bv = bias[g];
            for (int r = 0; r < 16; r++)
                out[(size_t)(r0 + r) * G4 + g] = acc[q][r] + bv;
        }
    }
}

// ---------------- K3: LSTM recurrence, 2 blocks/CU for tail overlap ------
// r13 schedule (2 superphases/step, 1 barrier each: act-first -> compute ->
// fill-poll) with HALVED blocks: 16 slices (8x13 + 8x12 units) x 32 pair-
// groups = 512 blocks x 512 threads. Waves 0-6 compute (cols c = wid+7j,
// c < 4U), wave 7 acts (U lanes). wlds declared 72KB so EXACTLY 2 blocks
// pack per CU (3x72 > 160KB): one block's compute fills the other's
// barrier/poll tail — the ~1050-cyc dead time in the 1-block/CU r13 layout.
// Packing is perfect (512 blocks = 256 CUs x capacity 2, greedy dispatch
// cannot strand capacity) so spin-sync co-residency is safe.
// Data-flag sync: hout NaN-filled per launch; write-once addresses; all
// LDS regions readable by lane over-reads are zero-filled (r15 lesson).
__global__ __launch_bounds__(512)
void lstm_k(const float* __restrict__ xgf, const float* __restrict__ xgb,
            const float* __restrict__ Whh_f, const float* __restrict__ Whh_b,
            float* __restrict__ hf, float* __restrict__ hb) {
    __shared__ float4 wlds[4500];                 // 72000B; slots [0,2664) used
    __shared__ __align__(16) float hsA[256];
    __shared__ __align__(16) float hsB[256];
    __shared__ __align__(16) float gbA[64];       // [gate*U + unit]
    __shared__ __align__(16) float gbB[64];

    const int blk = blockIdx.x;
    const int sl  = blk >> 5;                     // slice 0..15
    const int pg  = blk & 31;                     // dir*16 + pair; XCD = pg%8
    const int dir = pg >> 4;
    const int bA  = pg & 15;
    const int bB  = bA + 16;
    const int U    = (sl < 8) ? 13 : 12;          // units in this slice
    const int base = (sl < 8) ? 13 * sl : 104 + 12 * (sl - 8);
    const int C    = 4 * U;                       // gate-columns in this block
    const float* xg  = dir ? xgb : xgf;
    const float* Whh = dir ? Whh_b : Whh_f;
    float* hout      = dir ? hb : hf;

    const int t = threadIdx.x;
    const int lane = t & 63;
    const int wid = t >> 6;                       // wave id 0..7

    // stage weights: wlds[col*50+l] = Whh[row(col)][4l..4l+3]
    // col = gate*U+unit -> row = gate*200 + base + unit.
    // Slots [50C, 2664): ZEROED (lane>=50 over-reads must be finite).
    for (int i = t; i < 2664; i += 512) {
        float4 v = {0.f, 0.f, 0.f, 0.f};
        if (i < 50 * C) {
            int col = i / 50, l = i - col * 50;
            int row = (col / U) * 200 + base + (col % U);
            v = *(const float4*)(Whh + (size_t)row * HD + 4 * l);
        }
        wlds[i] = v;
    }
    if (t < 256) { hsA[t] = 0.f; hsB[t] = 0.f; }
    if (t < 64)  { gbA[t] = 0.f; gbB[t] = 0.f; }

    const bool is_act = (t >= 448) && (t < 448 + U);  // wave 7, lanes 0..U-1
    const int u = t - 448;
    const bool fill = (t < 200) && (t < base || t >= base + U);
    float cstA = 0.f, cstB = 0.f;
    float xA0=0,xA1=0,xA2=0,xA3=0, xB0=0,xB1=0,xB2=0,xB3=0;
    if (is_act) {
        int ts0 = dir ? (S - 1) : 0;
        const float* pa = xg + ((size_t)bA * S + ts0) * G4 + base + u;
        const float* pb = xg + ((size_t)bB * S + ts0) * G4 + base + u;
        xA0 = pa[0]; xA1 = pa[200]; xA2 = pa[400]; xA3 = pa[600];
        xB0 = pb[0]; xB1 = pb[200]; xB2 = pb[400]; xB3 = pb[600];
    }
    __syncthreads();

#define COMPUTE(hsX, gbX)                                                      \
    {                                                                          \
        float4 hv = ((const float4*)hsX)[lane];                                \
        _Pragma("unroll")                                                      \
        for (int j = 0; j < 8; j++) {                                          \
            int c = wid + 7 * j;                                               \
            if (c < C) {                                                       \
                float4 wv = wlds[c * 50 + lane];                               \
                float a = wave_sum64(dot4(wv, hv));                            \
                if (lane == 63) gbX[c] = a;                                    \
            }                                                                  \
        }                                                                      \
    }

#define POLL(dst, srcp)                                                        \
    {                                                                          \
        float v_;                                                              \
        do { v_ = __hip_atomic_load(srcp, __ATOMIC_RELAXED,                    \
                                    __HIP_MEMORY_SCOPE_AGENT); } while (v_ != v_); \
        dst = v_;                                                              \
    }

    for (int s = 0; s < S; s++) {
        const int ts  = dir ? (S - 1 - s) : s;          // time of step s
        const int tsp = dir ? (S - s)     : (s - 1);    // time of step s-1
        const int tsn = (s + 1 < S) ? (dir ? (S - 2 - s) : (s + 1)) : ts;

        // ======== SP0: act B(s-1) | compute A(s) | fill hsB <- h_B(s-1) ====
        if (is_act && s > 0) {
            float ig = fsig(gbB[u] + xB0);
            float fg = fsig(gbB[U + u] + xB1);
            float gt = ftanh(gbB[2 * U + u] + xB2);
            float og = fsig(gbB[3 * U + u] + xB3);
            cstB = fg * cstB + ig * gt;
            float h = og * ftanh(cstB);
            hsB[base + u] = h;
            __hip_atomic_store(&hout[((size_t)bB * S + tsp) * HD + base + u], h,
                               __ATOMIC_RELAXED, __HIP_MEMORY_SCOPE_AGENT);
            const float* pn = xg + ((size_t)bB * S + ts) * G4 + base + u;
            xB0 = pn[0]; xB1 = pn[200]; xB2 = pn[400]; xB3 = pn[600];
        }
        if (wid < 7) COMPUTE(hsA, gbA)
        if (s > 0 && fill) POLL(hsB[t], hout + ((size_t)bB * S + tsp) * HD + t)
        __syncthreads();

        // ======== SP1: act A(s) | compute B(s) | fill hsA <- h_A(s) ========
        if (is_act) {
            float ig = fsig(gbA[u] + xA0);
            float fg = fsig(gbA[U + u] + xA1);
            float gt = ftanh(gbA[2 * U + u] + xA2);
            float og = fsig(gbA[3 * U + u] + xA3);
            cstA = fg * cstA + ig * gt;
            float h = og * ftanh(cstA);
            hsA[base + u] = h;
            __hip_atomic_store(&hout[((size_t)bA * S + ts) * HD + base + u], h,
                               __ATOMIC_RELAXED, __HIP_MEMORY_SCOPE_AGENT);
            const float* pn = xg + ((size_t)bA * S + tsn) * G4 + base + u;
            xA0 = pn[0]; xA1 = pn[200]; xA2 = pn[400]; xA3 = pn[600];
        }
        if (wid < 7) COMPUTE(hsB, gbB)
        if (fill) POLL(hsA[t], hout + ((size_t)bA * S + ts) * HD + t)
        __syncthreads();
    }
    // epilogue: act B(S-1) (gbB from SP1(S-1), xB prefetched in SP0(S-1))
    if (is_act) {
        const int tl = dir ? 0 : (S - 1);
        float ig = fsig(gbB[u] + xB0);
        float fg = fsig(gbB[U + u] + xB1);
        float gt = ftanh(gbB[2 * U + u] + xB2);
        float og = fsig(gbB[3 * U + u] + xB3);
        cstB = fg * cstB + ig * gt;
        float h = og * ftanh(cstB);
        __hip_atomic_store(&hout[((size_t)bB * S + tl) * HD + base + u], h,
                           __ATOMIC_RELAXED, __HIP_MEMORY_SCOPE_AGENT);
    }
#undef COMPUTE
#undef POLL
}

// ---------------- K4: span features + subword emb + FFN ----------------
__global__ void out_k(const int* __restrict__ subwords,
                      const float* __restrict__ pre_w, const float* __restrict__ sub_w,
                      const float* __restrict__ hf, const float* __restrict__ hb,
                      const float* __restrict__ ffn_w, const float* __restrict__ ffn_b,
                      float* __restrict__ out) {
    int wave = (blockIdx.x * 256 + threadIdx.x) >> 6;
    int lane = threadIdx.x & 63;
    if (wave >= B * SK * W) return;
    int i = wave % W;
    int bk = wave / W;
    int k = bk % SK;
    int b = bk / SK;
    int end = k + i;
    float vscale = (end <= S - 3) ? 1.f : 0.f;
    int e1 = min(end + 1, S - 1);
    int e2 = min(end + 2, S - 1);
    const float* hfb = hf + (size_t)b * S * HD;
    const float* hbb = hb + (size_t)b * S * HD;
    int sw = subwords[wave];
    int sw2 = (sw >= SUBV) ? UNK : sw;
    float acc0 = 0, acc1 = 0, acc2 = 0, acc3 = 0;
    for (int j = lane; j < FEAT; j += 64) {
        float fv;
        if (j < HD) {
            fv = (hfb[(size_t)e1 * HD + j] - hfb[(size_t)k * HD + j]) * vscale;
        } else if (j < 2 * HD) {
            int jj = j - HD;
            fv = (hbb[(size_t)(k + 1) * HD + jj] - hbb[(size_t)e2 * HD + jj]) * vscale;
        } else {
            int jj = j - 2 * HD;
            fv = pre_w[(size_t)sw * SE + jj] + sub_w[(size_t)sw2 * SE + jj];
        }
        acc0 += ffn_w[j] * fv;
        acc1 += ffn_w[FEAT + j] * fv;
        acc2 += ffn_w[2 * FEAT + j] * fv;
        acc3 += ffn_w[3 * FEAT + j] * fv;
    }
    for (int off = 32; off; off >>= 1) {
        acc0 += __shfl_down(acc0, off);
        acc1 += __shfl_down(acc1, off);
        acc2 += __shfl_down(acc2, off);
        acc3 += __shfl_down(acc3, off);
    }
    if (lane == 0) {
        float* o = out + (size_t)wave * NL;
        o[0] = acc0 + ffn_b[0];
        o[1] = acc1 + ffn_b[1];
        o[2] = acc2 + ffn_b[2];
        o[3] = acc3 + ffn_b[3];
    }
}

extern "C" void kernel_launch(void* const* d_in, const int* in_sizes, int n_in,
                              void* d_out, int out_size, void* d_ws, size_t ws_size,
                              hipStream_t stream) {
    const int*   chars    = (const int*)d_in[0];
    const int*   bichars  = (const int*)d_in[1];
    const int*   subwords = (const int*)d_in[2];
    const float* cw    = (const float*)d_in[3];
    const float* bw    = (const float*)d_in[4];
    const float* subw  = (const float*)d_in[5];
    const float* prew  = (const float*)d_in[6];
    const float* Wih_f = (const float*)d_in[7];
    const float* Whh_f = (const float*)d_in[8];
    const float* b_f   = (const float*)d_in[9];
    const float* Wih_b = (const float*)d_in[10];
    const float* Whh_b = (const float*)d_in[11];
    const float* b_b   = (const float*)d_in[12];
    const float* ffn_w = (const float*)d_in[13];
    const float* ffn_b = (const float*)d_in[14];
    float* out = (float*)d_out;

    float* ws = (float*)d_ws;
    unsigned* WTh_f = (unsigned*)ws;         // 80000 u32 each (packed f16)
    unsigned* WTh_b = WTh_f + 80000;
    float* xgf = (float*)(WTh_b + 80000);    // 13,107,200
    float* xgb = xgf + 13107200;             // 13,107,200
    float* hf  = xgb + 13107200;             // 3,276,800
    float* hb  = hf + 3276800;               // 3,276,800 (contiguous with hf)

    // NaN-fill h buffers (one fused memset: hf|hb contiguous) — the data
    // word itself is the readiness flag for the lstm spin-sync.
    (void)hipMemsetAsync(hf, 0xFF, 2 * 3276800 * sizeof(float), stream);
    transpose_pack_k<<<313, 256, 0, stream>>>(Wih_f, WTh_f);
    transpose_pack_k<<<313, 256, 0, stream>>>(Wih_b, WTh_b);
    xg_k<<<dim3(B * S / 16, 2), 256, 0, stream>>>(chars, bichars, cw, bw,
                                                  WTh_f, b_f, WTh_b, b_b, xgf, xgb);
    lstm_k<<<512, 512, 0, stream>>>(xgf, xgb, Whh_f, Whh_b, hf, hb);
    out_k<<<(B * SK * W) / 4, 256, 0, stream>>>(subwords, prew, subw, hf, hb, ffn_w, ffn_b, out);
}